// Round 2
// baseline (524.161 us; speedup 1.0000x reference)
//
#include <hip/hip_runtime.h>

// ResLSTM: B=4096, T=512, H=32. One wave64 per batch element.
// Lane l computes gate rows l and l+64:
//   lanes 0..31:  row l = i,  row l+64 = g
//   lanes 32..63: row l = f,  row l+64 = o
//
// R4: h-broadcast via LDS same-address ds_read_b128, 407 -> 330 us.
// R5: waves_per_eu(4,4), 330 -> 316.
// R7: volatile weight pins, 341-357 us. POST-MORTEM R9: R7 sits exactly at
//   the LDS-pipe floor: 16 waves/CU x (8 b128 + 1 write + 2 permute) ~ 1630
//   cy/CU-step == measured 1600. LDS pipe saturated, VALU 72%.
// R8: readlane->hs[] broadcast FAILED (406 us, VALU 87%): compiler bounced
//   every uniform h through v_mov into VGPRs (32 readlane + 32 mov per step)
//   instead of using the single-SGPR source slot of v_fma_f32.
// R9 (this round): same broadcast, but FORCE SGPR consumption with inline
//   asm "v_fma_f32 %0, %1, %2, %0" (+v, v, s). Broadcast cost becomes the
//   minimal 32 readlanes; MACs read h straight from SGPRs; zero movs, zero
//   LDS in the recurrence. Predicted ~1000 cy/CU-step -> ~215-250 us,
//   VALUBusy ~90%, bitwise-identical output (same FMA order as R7/R8).

static constexpr int T_LEN = 512;
static constexpr int H = 32;

__device__ __forceinline__ float rl_c(float v, int l) {
    return __int_as_float(__builtin_amdgcn_readlane(__float_as_int(v), l));
}

// exp2-based sigmoid: sigmoid(x) = rcp(1 + exp2(x * -log2(e)))
__device__ __forceinline__ float sig_e2(float x_times_nlog2e) {
    return __builtin_amdgcn_rcpf(1.0f + __builtin_amdgcn_exp2f(x_times_nlog2e));
}

__global__ void
__attribute__((amdgpu_flat_work_group_size(256, 256), amdgpu_waves_per_eu(4, 4)))
reslstm_kernel(const float* __restrict__ x,
               const float* __restrict__ W_ih,
               const float* __restrict__ W_hh,
               const float* __restrict__ b_ih,
               const float* __restrict__ b_hh,
               const float* __restrict__ W_fc,
               const float* __restrict__ b_fc,
               float* __restrict__ out, int B)
{
    const int lane = threadIdx.x & 63;
    const int wv   = threadIdx.x >> 6;
    const int b    = (blockIdx.x << 2) + wv;
    if (b >= B) return;                       // wave-uniform guard

    const int r0 = lane;                      // i | f
    const int r1 = lane + 64;                 // g | o

    // W_hh rows for this lane -> 64 VGPR-resident floats (loaded as float4).
    const float4* pa = reinterpret_cast<const float4*>(W_hh + r0 * H);
    const float4* pb = reinterpret_cast<const float4*>(W_hh + r1 * H);
    float wa[32], wq[32];
    #pragma unroll
    for (int k = 0; k < 8; ++k) {
        const float4 ta = pa[k], tq = pb[k];
        wa[4*k+0] = ta.x; wa[4*k+1] = ta.y; wa[4*k+2] = ta.z; wa[4*k+3] = ta.w;
        wq[4*k+0] = tq.x; wq[4*k+1] = tq.y; wq[4*k+2] = tq.z; wq[4*k+3] = tq.w;
    }

    float wih0  = W_ih[r0];
    float wih1  = W_ih[r1];
    float bias0 = b_ih[r0] + b_hh[r0];
    float bias1 = b_ih[r1] + b_hh[r1];

    // Branchless tanh-vs-sigmoid for the r1 gate: tanh(x)=2*sigmoid(2x)-1.
    const bool lo = (lane < 32);
    constexpr float NL2E = -1.4426950408889634f;
    float e1 = lo ? 2.0f * NL2E : NL2E;
    float s1 = lo ? 2.0f : 1.0f;
    float t1 = lo ? -1.0f : 0.0f;

    // h(t-1) broadcast: hs[j] = readlane(h, j), kept in SGPRs. Consumed ONLY
    // through the "s" operand of the asm FMA below -> no v_mov copies.
    float hs[32];
    #pragma unroll
    for (int j = 0; j < 32; ++j) hs[j] = 0.0f;   // h0 = 0
    float h = 0.0f, c = 0.0f;

    const float* xrow = x + (size_t)b * T_LEN;

// Volatile pins: executed once per iteration, outputs feed next iteration.
// Reloading these from memory is illegal -> all 64 weight floats + 7 loop
// scalars MUST stay VGPR-resident. (hs[] deliberately NOT pinned: "+v"
// would force the uniform values into VGPRs.)
#define PIN16(P)                                                              \
    asm volatile("" : "+v"((P)[0]),  "+v"((P)[1]),  "+v"((P)[2]),  "+v"((P)[3]), \
                      "+v"((P)[4]),  "+v"((P)[5]),  "+v"((P)[6]),  "+v"((P)[7]), \
                      "+v"((P)[8]),  "+v"((P)[9]),  "+v"((P)[10]), "+v"((P)[11]),\
                      "+v"((P)[12]), "+v"((P)[13]), "+v"((P)[14]), "+v"((P)[15]))
#define PINALL()                                                              \
    PIN16(wa); PIN16(wa + 16); PIN16(wq); PIN16(wq + 16);                     \
    asm volatile("" : "+v"(wih0), "+v"(wih1), "+v"(bias0), "+v"(bias1),       \
                      "+v"(e1), "+v"(s1), "+v"(t1))

// MAC with scalar-broadcast h: v_fma_f32 vdst, vsrc, ssrc, vdst.
// VOP3 allows exactly one SGPR source -> legal, single instruction, no mov.
// Non-volatile asm: scheduler may reorder on dataflow.
#define FMA_S(acc, w_, h_)                                                    \
    asm("v_fma_f32 %0, %1, %2, %0" : "+v"(acc) : "v"(w_), "s"(h_))

    for (int tc = 0; tc < T_LEN / 64; ++tc) {
        const float xv = xrow[(tc << 6) + lane];   // coalesced 64-float chunk
        #pragma unroll 4
        for (int tt = 0; tt < 64; ++tt) {
            PINALL();                              // force weight residency
            const float xt = rl_c(xv, tt);         // x[b][t], wave-uniform
            float aA  = __builtin_fmaf(xt, wih0, bias0);
            float aB  = __builtin_fmaf(xt, wih1, bias1);
            float aA2 = 0.0f, aB2 = 0.0f;
            // Same accumulation order as R7/R8 (even j -> aA, odd j -> aA2):
            // bitwise-identical gate pre-activations.
            #pragma unroll
            for (int j = 0; j < 32; j += 2) {
                FMA_S(aA,  wa[j],   hs[j]);
                FMA_S(aB,  wq[j],   hs[j]);
                FMA_S(aA2, wa[j+1], hs[j+1]);
                FMA_S(aB2, wq[j+1], hs[j+1]);
            }
            aA += aA2; aB += aB2;
            const float g0 = sig_e2(aA * NL2E);                       // i | f
            const float g1 = __builtin_fmaf(s1, sig_e2(aB * e1), t1); // g | o
            const float fo = __shfl_xor(g0, 32);   // lanes<32 get f[j]
            const float og = __shfl_xor(g1, 32);   // lanes<32 get o[j]
            // lanes>=32 carry bounded garbage c,h; their h is never
            // readlane'd (broadcast sources lanes 0..31 only).
            c = __builtin_fmaf(fo, c, g0 * g1);                       // f*c+i*g
            const float th = __builtin_fmaf(2.0f, sig_e2(c * (2.0f * NL2E)), -1.0f);
            h = og * th;                                              // o*tanh(c)
            // publish h for next step: lane j -> SGPR hs[j] (1 readlane per
            // value, no LDS, no movs -- minimal broadcast cost)
            #pragma unroll
            for (int j = 0; j < 32; ++j) hs[j] = rl_c(h, j);
        }
    }
#undef FMA_S
#undef PINALL
#undef PIN16

    // out[b] = sum_j h[j]*W_fc[j] + b_fc  (butterfly reduce over the wave)
    float val = lo ? h * W_fc[lane & (H - 1)] : 0.0f;
    #pragma unroll
    for (int off = 32; off >= 1; off >>= 1)
        val += __shfl_xor(val, off);
    if (lane == 0) out[b] = val + b_fc[0];
}

extern "C" void kernel_launch(void* const* d_in, const int* in_sizes, int n_in,
                              void* d_out, int out_size, void* d_ws, size_t ws_size,
                              hipStream_t stream) {
    const float* x    = (const float*)d_in[0];
    const float* W_ih = (const float*)d_in[1];
    const float* W_hh = (const float*)d_in[2];
    const float* b_ih = (const float*)d_in[3];
    const float* b_hh = (const float*)d_in[4];
    const float* W_fc = (const float*)d_in[5];
    const float* b_fc = (const float*)d_in[6];
    float* out = (float*)d_out;
    const int B = in_sizes[0] / T_LEN;        // 4096
    dim3 block(256);                          // 4 waves = 4 batch elements
    dim3 grid((B + 3) / 4);                   // 1024 blocks -> 4 waves/SIMD
    reslstm_kernel<<<grid, block, 0, stream>>>(x, W_ih, W_hh, b_ih, b_hh,
                                               W_fc, b_fc, out, B);
}

// Round 3
// 438.558 us; speedup vs baseline: 1.1952x; 1.1952x over previous
//
#include <hip/hip_runtime.h>

// ResLSTM: B=4096, T=512, H=32. One wave64 per batch element.
// Lane l computes gate rows l and l+64:
//   lanes 0..31:  row l = i,  row l+64 = g
//   lanes 32..63: row l = f,  row l+64 = o
//
// R4: h-broadcast via LDS same-address ds_read_b128, 407 -> 330 us.
// R5: waves_per_eu(4,4), 330 -> 316.  R7: volatile weight pins, 341.
//   POST-MORTEM: R7 sits exactly at the LDS-pipe floor: 16 waves/CU x
//   (8 b128 + 1 write + 2 permute) ~ 1630 cy/CU-step == measured 1600.
// R8: readlane->VGPR-mov broadcast: 406 us (64 extra VALU ops/step).
// R9: readlane->SGPR-consuming asm FMA: 503 us (VALU-writes-SGPR ->
//   VALU-reads-SGPR hazard wait states on all 64 MACs). SGPR path dead.
// R10 (this round): SYSTOLIC ROTATION. h lives as a two-copy VGPR
//   (hrot[l] = h[l&31]) which is invariant under full-wave DPP rotation
//   (wave_ror:1). Per MAC k, lane l holds h[(l+sgn*k)&31]; weights are
//   preloaded per-lane pre-rotated so every MAC is a register-only
//   v_fmac + one v_mov_dpp per k. Rotation direction is probed at
//   runtime (mov_dpp on lane id) so the ISA convention can't flip
//   results. LDS pipe now carries only 3 shfl ops/step (was 11).
//   Predicted ~1080 cy/CU-step vs R7's 1600 -> ~230 us, VALUBusy >90%.
//   NOTE: per-lane accumulation order rotates (starts at j=lane) ->
//   bitwise identity with reference may be lost; expected absmax <~1e-5.

static constexpr int T_LEN = 512;
static constexpr int H = 32;

__device__ __forceinline__ float rl_c(float v, int l) {
    return __int_as_float(__builtin_amdgcn_readlane(__float_as_int(v), l));
}

// exp2-based sigmoid: sigmoid(x) = rcp(1 + exp2(x * -log2(e)))
__device__ __forceinline__ float sig_e2(float x_times_nlog2e) {
    return __builtin_amdgcn_rcpf(1.0f + __builtin_amdgcn_exp2f(x_times_nlog2e));
}

// Full-wave rotate by one lane via DPP (0x13C = wave_ror:1, all rows/banks).
__device__ __forceinline__ float ror1(float v) {
    return __int_as_float(__builtin_amdgcn_mov_dpp(
        __float_as_int(v), 0x13C, 0xF, 0xF, false));
}

__global__ void
__attribute__((amdgpu_flat_work_group_size(256, 256), amdgpu_waves_per_eu(4, 4)))
reslstm_kernel(const float* __restrict__ x,
               const float* __restrict__ W_ih,
               const float* __restrict__ W_hh,
               const float* __restrict__ b_ih,
               const float* __restrict__ b_hh,
               const float* __restrict__ W_fc,
               const float* __restrict__ b_fc,
               float* __restrict__ out, int B)
{
    const int lane = threadIdx.x & 63;
    const int wv   = threadIdx.x >> 6;
    const int b    = (blockIdx.x << 2) + wv;
    if (b >= B) return;                       // wave-uniform guard

    const int r0 = lane;                      // i | f
    const int r1 = lane + 64;                 // g | o

    // --- Rotation-direction probe (2 instr, once per kernel) ---
    // If wave_ror:1 delivers lane (l+1)&63 -> efter k rotations the
    // two-copy register holds h[(l+k)&31] -> weight index (lane+k)&31.
    // If the convention is the other way -> (lane-k)&31.
    const int det  = __builtin_amdgcn_mov_dpp(lane, 0x13C, 0xF, 0xF, false);
    const int from = __builtin_amdgcn_readlane(det, 0);   // 1 or 63
    const int sgn  = (from == 1) ? 1 : -1;

    // Weights preloaded per-lane PRE-ROTATED: wa[k] = W_hh[r0][(lane+sgn*k)&31].
    // Scalar loads; W_hh is 16 KB -> L2-resident, one-time cost.
    float wa[32], wq[32];
    #pragma unroll
    for (int k = 0; k < 32; ++k) {
        const int idx = (lane + sgn * k) & (H - 1);
        wa[k] = W_hh[r0 * H + idx];
        wq[k] = W_hh[r1 * H + idx];
    }

    float wih0  = W_ih[r0];
    float wih1  = W_ih[r1];
    float bias0 = b_ih[r0] + b_hh[r0];
    float bias1 = b_ih[r1] + b_hh[r1];

    // Branchless tanh-vs-sigmoid for the r1 gate: tanh(x)=2*sigmoid(2x)-1.
    const bool lo = (lane < 32);
    constexpr float NL2E = -1.4426950408889634f;
    float e1 = lo ? 2.0f * NL2E : NL2E;
    float s1 = lo ? 2.0f : 1.0f;
    float t1 = lo ? -1.0f : 0.0f;

    float h = 0.0f, c = 0.0f;
    float hrot = 0.0f;                        // two-copy broadcast of h(t-1)

    const float* xrow = x + (size_t)b * T_LEN;

// Volatile pins: executed once per iteration, outputs feed next iteration.
// Reloading these from memory is illegal -> all 64 weight floats + 7 loop
// scalars MUST stay VGPR-resident.
#define PIN16(P)                                                              \
    asm volatile("" : "+v"((P)[0]),  "+v"((P)[1]),  "+v"((P)[2]),  "+v"((P)[3]), \
                      "+v"((P)[4]),  "+v"((P)[5]),  "+v"((P)[6]),  "+v"((P)[7]), \
                      "+v"((P)[8]),  "+v"((P)[9]),  "+v"((P)[10]), "+v"((P)[11]),\
                      "+v"((P)[12]), "+v"((P)[13]), "+v"((P)[14]), "+v"((P)[15]))
#define PINALL()                                                              \
    PIN16(wa); PIN16(wa + 16); PIN16(wq); PIN16(wq + 16);                     \
    asm volatile("" : "+v"(wih0), "+v"(wih1), "+v"(bias0), "+v"(bias1),       \
                      "+v"(e1), "+v"(s1), "+v"(t1))

    for (int tc = 0; tc < T_LEN / 64; ++tc) {
        const float xv = xrow[(tc << 6) + lane];   // coalesced 64-float chunk
        #pragma unroll 4
        for (int tt = 0; tt < 64; ++tt) {
            PINALL();                              // force weight residency
            const float xt = rl_c(xv, tt);         // x[b][t], wave-uniform
            float aA  = __builtin_fmaf(xt, wih0, bias0);
            float aB  = __builtin_fmaf(xt, wih1, bias1);
            float aA2 = 0.0f, aB2 = 0.0f;
            // Systolic MAC: hr holds h[(lane+sgn*k)&31]; weights were
            // preloaded in matching rotated order. Even k -> aA/aB,
            // odd k -> aA2/aB2 (two dependency chains).
            float hr = hrot;
            #pragma unroll
            for (int k = 0; k < 32; k += 2) {
                aA  = __builtin_fmaf(wa[k],   hr, aA);
                aB  = __builtin_fmaf(wq[k],   hr, aB);
                hr  = ror1(hr);
                aA2 = __builtin_fmaf(wa[k+1], hr, aA2);
                aB2 = __builtin_fmaf(wq[k+1], hr, aB2);
                if (k + 2 < 32) hr = ror1(hr);     // 31 rotations total
            }
            aA += aA2; aB += aB2;
            const float g0 = sig_e2(aA * NL2E);                       // i | f
            const float g1 = __builtin_fmaf(s1, sig_e2(aB * e1), t1); // g | o
            const float fo = __shfl_xor(g0, 32);   // lanes<32 get f[j]
            const float og = __shfl_xor(g1, 32);   // lanes<32 get o[j]
            // lanes>=32 carry bounded garbage c,h; hrot is rebuilt from
            // the valid lower-half h each step.
            c = __builtin_fmaf(fo, c, g0 * g1);                       // f*c+i*g
            const float th = __builtin_fmaf(2.0f, sig_e2(c * (2.0f * NL2E)), -1.0f);
            h = og * th;                                              // o*tanh(c)
            // Rebuild two-copy broadcast: hrot[l] = h[l&31].
            const float hx = __shfl_xor(h, 32);    // upper lanes: lower h
            hrot = lo ? h : hx;
        }
    }
#undef PINALL
#undef PIN16

    // out[b] = sum_j h[j]*W_fc[j] + b_fc  (butterfly reduce over the wave)
    float val = lo ? h * W_fc[lane & (H - 1)] : 0.0f;
    #pragma unroll
    for (int off = 32; off >= 1; off >>= 1)
        val += __shfl_xor(val, off);
    if (lane == 0) out[b] = val + b_fc[0];
}

extern "C" void kernel_launch(void* const* d_in, const int* in_sizes, int n_in,
                              void* d_out, int out_size, void* d_ws, size_t ws_size,
                              hipStream_t stream) {
    const float* x    = (const float*)d_in[0];
    const float* W_ih = (const float*)d_in[1];
    const float* W_hh = (const float*)d_in[2];
    const float* b_ih = (const float*)d_in[3];
    const float* b_hh = (const float*)d_in[4];
    const float* W_fc = (const float*)d_in[5];
    const float* b_fc = (const float*)d_in[6];
    float* out = (float*)d_out;
    const int B = in_sizes[0] / T_LEN;        // 4096
    dim3 block(256);                          // 4 waves = 4 batch elements
    dim3 grid((B + 3) / 4);                   // 1024 blocks -> 4 waves/SIMD
    reslstm_kernel<<<grid, block, 0, stream>>>(x, W_ih, W_hh, b_ih, b_hh,
                                               W_fc, b_fc, out, B);
}

// Round 4
// 310.713 us; speedup vs baseline: 1.6870x; 1.4115x over previous
//
#include <hip/hip_runtime.h>

// ResLSTM: B=4096, T=512, H=32.
// R11 STRUCTURE: one wave64 handles TWO batch elements.
//   half = lane>>5 selects the batch (b0 or b0+1), j = lane&31 is the
//   hidden unit. Lane (half,j) owns ALL FOUR gate rows of unit j:
//   i=row j, f=row j+32, g=row j+64, o=row j+96  (PyTorch i,f,g,o order).
// Why: R7 (341 us) was LDS-pipe-bound: 16 waves/CU x (8 b128 h-broadcast
//   + write + 2 shfl) ~ 1600 cy/CU-step == measured wall. R8/R9/R10 showed
//   readlane/SGPR/DPP broadcasts are all worse than LDS. So AMORTIZE the
//   LDS broadcast instead: one broadcast now feeds 2 batch-steps, the
//   gate shfl_xor pair is eliminated (gates are lane-local), and trans
//   overhead per batch halves. Per-CU-step demand: LDS ~720 cy, VALU
//   ~680 cy/SIMD vs R7's 1600 -> predicted ~160 us.
// Cost: 2048 waves total -> 2 waves/SIMD occupancy; per-step tail latency
//   (~150 cy) must hide under the co-resident wave's ~340 cy issue.

static constexpr int T_LEN = 512;
static constexpr int H = 32;

// exp2-based sigmoid: sigmoid(x) = rcp(1 + exp2(x * -log2(e)))
__device__ __forceinline__ float sig_e2(float x_times_nlog2e) {
    return __builtin_amdgcn_rcpf(1.0f + __builtin_amdgcn_exp2f(x_times_nlog2e));
}

__global__ void
__attribute__((amdgpu_flat_work_group_size(256, 256), amdgpu_waves_per_eu(2, 2)))
reslstm_kernel(const float* __restrict__ x,
               const float* __restrict__ W_ih,
               const float* __restrict__ W_hh,
               const float* __restrict__ b_ih,
               const float* __restrict__ b_hh,
               const float* __restrict__ W_fc,
               const float* __restrict__ b_fc,
               float* __restrict__ out, int B)
{
    // Per-wave staging. Halves padded 36 floats (144 B) apart: the two
    // same-address broadcast groups land on different banks (+4), and the
    // 64-lane h-write is a uniform 2-way bank alias (free per m136).
    __shared__ float hbuf[4][2][36];   // [wave][half][unit]
    __shared__ float xbuf[4][72];      // [wave][half*36 + j] : 32-step x chunk

    const int lane = threadIdx.x & 63;
    const int wv   = threadIdx.x >> 6;
    const int j    = lane & 31;       // hidden unit
    const int half = lane >> 5;       // which batch of the pair

    const int b0 = (blockIdx.x << 3) + (wv << 1);
    if (b0 >= B) return;              // wave-uniform guard
    const int bb   = b0 + half;
    const int bsrc = (bb < B) ? bb : b0;   // clamp loads; store is guarded

    // W_hh rows for unit j, all four gates -> 32 float4 = 128 VGPRs.
    const float4* pwi = reinterpret_cast<const float4*>(W_hh + (j     ) * H);
    const float4* pwf = reinterpret_cast<const float4*>(W_hh + (j + 32) * H);
    const float4* pwg = reinterpret_cast<const float4*>(W_hh + (j + 64) * H);
    const float4* pwo = reinterpret_cast<const float4*>(W_hh + (j + 96) * H);
    float4 wi0=pwi[0], wi1=pwi[1], wi2=pwi[2], wi3=pwi[3],
           wi4=pwi[4], wi5=pwi[5], wi6=pwi[6], wi7=pwi[7];
    float4 wf0=pwf[0], wf1=pwf[1], wf2=pwf[2], wf3=pwf[3],
           wf4=pwf[4], wf5=pwf[5], wf6=pwf[6], wf7=pwf[7];
    float4 wg0=pwg[0], wg1=pwg[1], wg2=pwg[2], wg3=pwg[3],
           wg4=pwg[4], wg5=pwg[5], wg6=pwg[6], wg7=pwg[7];
    float4 wo0=pwo[0], wo1=pwo[1], wo2=pwo[2], wo3=pwo[3],
           wo4=pwo[4], wo5=pwo[5], wo6=pwo[6], wo7=pwo[7];

    float wihi = W_ih[j];      float wihf = W_ih[j + 32];
    float wihg = W_ih[j + 64]; float wiho = W_ih[j + 96];
    float bi  = b_ih[j]      + b_hh[j];
    float bfv = b_ih[j + 32] + b_hh[j + 32];
    float bgv = b_ih[j + 64] + b_hh[j + 64];
    float bov = b_ih[j + 96] + b_hh[j + 96];

    constexpr float NL2E  = -1.4426950408889634f;   // -log2(e)
    constexpr float N2L2E = 2.0f * NL2E;

    float h = 0.0f, c = 0.0f;
    hbuf[wv][half][j] = 0.0f;                 // h0 = 0 (wave-synchronous)

    const float* xrow = x + (size_t)bsrc * T_LEN;
    const float4* hb = reinterpret_cast<const float4*>(&hbuf[wv][half][0]);
    const float4* xb = reinterpret_cast<const float4*>(&xbuf[wv][half * 36]);

// Volatile pins: executed once per step; outputs feed the next step.
// Reloading pinned values from memory is illegal -> the 128 weight floats
// + 8 scalars stay VGPR-resident (R6/R7 lesson).
#define PINV4(P0, P1, P2, P3)                                             \
    asm volatile("" : "+v"(P0.x), "+v"(P0.y), "+v"(P0.z), "+v"(P0.w),     \
                      "+v"(P1.x), "+v"(P1.y), "+v"(P1.z), "+v"(P1.w),     \
                      "+v"(P2.x), "+v"(P2.y), "+v"(P2.z), "+v"(P2.w),     \
                      "+v"(P3.x), "+v"(P3.y), "+v"(P3.z), "+v"(P3.w))
#define PINALL()                                                          \
    PINV4(wi0, wi1, wi2, wi3); PINV4(wi4, wi5, wi6, wi7);                 \
    PINV4(wf0, wf1, wf2, wf3); PINV4(wf4, wf5, wf6, wf7);                 \
    PINV4(wg0, wg1, wg2, wg3); PINV4(wg4, wg5, wg6, wg7);                 \
    PINV4(wo0, wo1, wo2, wo3); PINV4(wo4, wo5, wo6, wo7);                 \
    asm volatile("" : "+v"(wihi), "+v"(wihf), "+v"(wihg), "+v"(wiho),     \
                      "+v"(bi), "+v"(bfv), "+v"(bgv), "+v"(bov))

// 16 FMAs against one broadcast float4 (x,z -> chain1; y,w -> chain2).
#define MACK(WI, WF, WG, WO, HV)                                          \
    ai  = __builtin_fmaf(WI.x, HV.x, ai);                                 \
    af_ = __builtin_fmaf(WF.x, HV.x, af_);                                \
    ag_ = __builtin_fmaf(WG.x, HV.x, ag_);                                \
    ao_ = __builtin_fmaf(WO.x, HV.x, ao_);                                \
    ai2 = __builtin_fmaf(WI.y, HV.y, ai2);                                \
    af2 = __builtin_fmaf(WF.y, HV.y, af2);                                \
    ag2 = __builtin_fmaf(WG.y, HV.y, ag2);                                \
    ao2 = __builtin_fmaf(WO.y, HV.y, ao2);                                \
    ai  = __builtin_fmaf(WI.z, HV.z, ai);                                 \
    af_ = __builtin_fmaf(WF.z, HV.z, af_);                                \
    ag_ = __builtin_fmaf(WG.z, HV.z, ag_);                                \
    ao_ = __builtin_fmaf(WO.z, HV.z, ao_);                                \
    ai2 = __builtin_fmaf(WI.w, HV.w, ai2);                                \
    af2 = __builtin_fmaf(WF.w, HV.w, af2);                                \
    ag2 = __builtin_fmaf(WG.w, HV.w, ag2);                                \
    ao2 = __builtin_fmaf(WO.w, HV.w, ao2);

#define STEP(XT) do {                                                     \
    PINALL();                                                             \
    float ai  = __builtin_fmaf(XT, wihi, bi);                             \
    float af_ = __builtin_fmaf(XT, wihf, bfv);                            \
    float ag_ = __builtin_fmaf(XT, wihg, bgv);                            \
    float ao_ = __builtin_fmaf(XT, wiho, bov);                            \
    float ai2 = 0.0f, af2 = 0.0f, ag2 = 0.0f, ao2 = 0.0f;                 \
    {   /* h(t-1) broadcast: same-address b128 per half, 2 groups of 4 */ \
        float4 h0 = hb[0], h1 = hb[1], h2 = hb[2], h3 = hb[3];            \
        MACK(wi0, wf0, wg0, wo0, h0) MACK(wi1, wf1, wg1, wo1, h1)         \
        MACK(wi2, wf2, wg2, wo2, h2) MACK(wi3, wf3, wg3, wo3, h3)         \
    }                                                                     \
    {                                                                     \
        float4 h4 = hb[4], h5 = hb[5], h6 = hb[6], h7 = hb[7];            \
        MACK(wi4, wf4, wg4, wo4, h4) MACK(wi5, wf5, wg5, wo5, h5)         \
        MACK(wi6, wf6, wg6, wo6, h6) MACK(wi7, wf7, wg7, wo7, h7)         \
    }                                                                     \
    ai += ai2; af_ += af2; ag_ += ag2; ao_ += ao2;                        \
    const float gi = sig_e2(ai  * NL2E);                                  \
    const float gf = sig_e2(af_ * NL2E);                                  \
    const float go = sig_e2(ao_ * NL2E);                                  \
    const float gg = __builtin_fmaf(2.0f, sig_e2(ag_ * N2L2E), -1.0f);    \
    c = __builtin_fmaf(gf, c, gi * gg);                                   \
    const float th = __builtin_fmaf(2.0f, sig_e2(c * N2L2E), -1.0f);      \
    h = go * th;                                                          \
    hbuf[wv][half][j] = h;            /* publish for next step */         \
} while (0)

    float xcur = xrow[j];                     // chunk 0 of this half's batch
    for (int tc = 0; tc < T_LEN / 32; ++tc) {
        xbuf[wv][half * 36 + j] = xcur;       // stage 32 steps of x
        float xnext = 0.0f;
        if (tc + 1 < T_LEN / 32) xnext = xrow[(tc + 1) * 32 + j];  // prefetch
        for (int t4 = 0; t4 < 8; ++t4) {
            const float4 xq = xb[t4];         // 4 steps of x, broadcast/half
            STEP(xq.x); STEP(xq.y); STEP(xq.z); STEP(xq.w);
        }
        xcur = xnext;
    }
#undef STEP
#undef MACK
#undef PINALL
#undef PINV4

    // out[bb] = sum_j h[j]*W_fc[j] + b_fc  (butterfly within each half)
    float val = h * W_fc[j];
    #pragma unroll
    for (int off = 16; off >= 1; off >>= 1)
        val += __shfl_xor(val, off);
    if (j == 0 && bb < B) out[bb] = val + b_fc[0];
}

extern "C" void kernel_launch(void* const* d_in, const int* in_sizes, int n_in,
                              void* d_out, int out_size, void* d_ws, size_t ws_size,
                              hipStream_t stream) {
    const float* x    = (const float*)d_in[0];
    const float* W_ih = (const float*)d_in[1];
    const float* W_hh = (const float*)d_in[2];
    const float* b_ih = (const float*)d_in[3];
    const float* b_hh = (const float*)d_in[4];
    const float* W_fc = (const float*)d_in[5];
    const float* b_fc = (const float*)d_in[6];
    float* out = (float*)d_out;
    const int B = in_sizes[0] / T_LEN;        // 4096
    dim3 block(256);                          // 4 waves = 8 batch elements
    dim3 grid((B + 7) / 8);                   // 512 blocks -> 2 waves/SIMD
    reslstm_kernel<<<grid, block, 0, stream>>>(x, W_ih, W_hh, b_ih, b_hh,
                                               W_fc, b_fc, out, B);
}

// Round 5
// 278.425 us; speedup vs baseline: 1.8826x; 1.1160x over previous
//
#include <hip/hip_runtime.h>

// ResLSTM: B=4096, T=512, H=32.  One wave64 = TWO batch elements.
//   half = lane>>5 selects the batch, j = lane&31 is the hidden unit;
//   lane (half,j) owns all four gate rows of unit j (i,f,g,o).
//
// History: R4 LDS h-broadcast 407->330. R5 waves_per_eu 330->316.
// R7 pins 341. R8/R9/R10 (readlane/SGPR/DPP broadcasts) all regressed ->
// LDS broadcast is the cheapest. R11 (2 batches/wave, gates lane-local):
// 341->297 us, VALUBusy 81% (1128 cy/SIMD-step busy of 1392 wall).
// Breakdown: 128 MAC fma = 256 cy (fp32-VALU floor), trans ~80, gates ~44,
// overhead ~180. MfmaUtil=0. v_pk_fma_f32 is half-rate on CDNA4 (FP32 peak
// 157.3 TF is non-packed) -> no fp32 packing win.
// R12 (this round): v_dot2_f32_f16 for the h@W_hh MAC ONLY.
//   - W_hh prescaled by -log2(e) (2x for g-gate) -> sigmoid scale muls fold
//     into the weights; stored as packed f16 pairs (64 VGPRs, was 128).
//   - h published to LDS as f16; broadcast = 4x ds_read_b128 (was 8).
//   - x-projection, biases, c, gate math all stay fp32.
//   MAC issue 256 -> 128 cy/wave-step. Predicted ~200 us (180-245) if dot2
//   is full-rate; ~270 (neutral) if half-rate. absmax expected ~1e-3
//   (f16 h/w, contractive recurrence) -- first non-bitwise round.

static constexpr int T_LEN = 512;
static constexpr int H = 32;

typedef _Float16 h2 __attribute__((ext_vector_type(2)));

// float bit-pattern -> packed f16 pair
__device__ __forceinline__ h2 bch(float f) { return __builtin_bit_cast(h2, f); }

// D = dot2(a, b) + c  : 2 f16 MACs, fp32 accumulate (v_dot2_f32_f16)
__device__ __forceinline__ float fd2(float wbits, h2 p, float acc) {
#if __has_builtin(__builtin_amdgcn_fdot2)
    return __builtin_amdgcn_fdot2(__builtin_bit_cast(h2, wbits), p, acc, false);
#else
    float d = acc;
    asm("v_dot2_f32_f16 %0, %1, %2, %0"
        : "+v"(d) : "v"(__builtin_bit_cast(h2, wbits)), "v"(p));
    return d;
#endif
}

// pack two fp32 (prescaled) weights into one f16-pair bit pattern
__device__ __forceinline__ float packw(float w0, float w1) {
    h2 p;
    p[0] = (_Float16)w0;
    p[1] = (_Float16)w1;
    return __builtin_bit_cast(float, p);
}

__global__ void
__attribute__((amdgpu_flat_work_group_size(256, 256), amdgpu_waves_per_eu(2, 2)))
reslstm_kernel(const float* __restrict__ x,
               const float* __restrict__ W_ih,
               const float* __restrict__ W_hh,
               const float* __restrict__ b_ih,
               const float* __restrict__ b_hh,
               const float* __restrict__ W_fc,
               const float* __restrict__ b_fc,
               float* __restrict__ out, int B)
{
    // h as f16: [wave][half][40] (pad 80 B -> halves' same-address broadcast
    // groups sit 20 banks apart; all four b128 reads conflict-free).
    __shared__ _Float16 hbufh[4][2][40];
    __shared__ float    xbuf[4][72];     // [wave][half*36 + j]: 32-step x chunk

    const int lane = threadIdx.x & 63;
    const int wv   = threadIdx.x >> 6;
    const int j    = lane & 31;          // hidden unit
    const int half = lane >> 5;          // which batch of the pair

    const int b0 = (blockIdx.x << 3) + (wv << 1);
    if (b0 >= B) return;                 // wave-uniform guard
    const int bb   = b0 + half;
    const int bsrc = (bb < B) ? bb : b0; // clamp loads; store is guarded

    constexpr float NL2E  = -1.4426950408889634f;   // -log2(e)
    constexpr float N2L2E = 2.0f * NL2E;

    // W_hh rows for unit j, all four gates, PRESCALED (i,f,o: *NL2E;
    // g: *2NL2E) and packed to f16 pairs -> 64 VGPRs total.
    float wi2[16], wf2[16], wg2[16], wo2[16];
    {
        const float* ri = W_hh + (j     ) * H;
        const float* rf = W_hh + (j + 32) * H;
        const float* rg = W_hh + (j + 64) * H;
        const float* ro = W_hh + (j + 96) * H;
        #pragma unroll
        for (int k = 0; k < 16; ++k) {
            wi2[k] = packw(ri[2*k] * NL2E,  ri[2*k+1] * NL2E);
            wf2[k] = packw(rf[2*k] * NL2E,  rf[2*k+1] * NL2E);
            wg2[k] = packw(rg[2*k] * N2L2E, rg[2*k+1] * N2L2E);
            wo2[k] = packw(ro[2*k] * NL2E,  ro[2*k+1] * NL2E);
        }
    }

    // x-projection weights & biases: fp32, prescaled.
    float wihi = W_ih[j]      * NL2E;
    float wihf = W_ih[j + 32] * NL2E;
    float wihg = W_ih[j + 64] * N2L2E;
    float wiho = W_ih[j + 96] * NL2E;
    float bi  = (b_ih[j]      + b_hh[j])      * NL2E;
    float bfv = (b_ih[j + 32] + b_hh[j + 32]) * NL2E;
    float bgv = (b_ih[j + 64] + b_hh[j + 64]) * N2L2E;
    float bov = (b_ih[j + 96] + b_hh[j + 96]) * NL2E;

    float h = 0.0f, c = 0.0f;
    hbufh[wv][half][j] = (_Float16)0.0f;      // h0 = 0 (wave-synchronous)

    const float* xrow = x + (size_t)bsrc * T_LEN;
    const float4* hb = reinterpret_cast<const float4*>(&hbufh[wv][half][0]);
    const float4* xb = reinterpret_cast<const float4*>(&xbuf[wv][half * 36]);

// Volatile pins (R6/R7 lesson): outputs feed the next step; reloading
// pinned values from memory is illegal -> weights stay VGPR-resident.
#define PIN16(P)                                                              \
    asm volatile("" : "+v"((P)[0]),  "+v"((P)[1]),  "+v"((P)[2]),  "+v"((P)[3]), \
                      "+v"((P)[4]),  "+v"((P)[5]),  "+v"((P)[6]),  "+v"((P)[7]), \
                      "+v"((P)[8]),  "+v"((P)[9]),  "+v"((P)[10]), "+v"((P)[11]),\
                      "+v"((P)[12]), "+v"((P)[13]), "+v"((P)[14]), "+v"((P)[15]))
#define PINALL()                                                              \
    PIN16(wi2); PIN16(wf2); PIN16(wg2); PIN16(wo2);                           \
    asm volatile("" : "+v"(wihi), "+v"(wihf), "+v"(wihg), "+v"(wiho),         \
                      "+v"(bi), "+v"(bfv), "+v"(bgv), "+v"(bov))

// 16 dot2 against one broadcast float4 (= 8 f16 = 4 h-pairs).
// Pairs M+0,M+2 -> chain1; M+1,M+3 -> chain2.
#define MACQ(HQ, M)                                                           \
    {   const h2 p0 = bch(HQ.x), p1 = bch(HQ.y),                              \
                 p2 = bch(HQ.z), p3 = bch(HQ.w);                              \
        a1i = fd2(wi2[M+0], p0, a1i); a1f = fd2(wf2[M+0], p0, a1f);           \
        a1g = fd2(wg2[M+0], p0, a1g); a1o = fd2(wo2[M+0], p0, a1o);           \
        a2i = fd2(wi2[M+1], p1, a2i); a2f = fd2(wf2[M+1], p1, a2f);           \
        a2g = fd2(wg2[M+1], p1, a2g); a2o = fd2(wo2[M+1], p1, a2o);           \
        a1i = fd2(wi2[M+2], p2, a1i); a1f = fd2(wf2[M+2], p2, a1f);           \
        a1g = fd2(wg2[M+2], p2, a1g); a1o = fd2(wo2[M+2], p2, a1o);           \
        a2i = fd2(wi2[M+3], p3, a2i); a2f = fd2(wf2[M+3], p3, a2f);           \
        a2g = fd2(wg2[M+3], p3, a2g); a2o = fd2(wo2[M+3], p3, a2o);           \
    }

#define STEP(XT) do {                                                         \
    PINALL();                                                                 \
    float a1i = __builtin_fmaf(XT, wihi, bi);                                 \
    float a1f = __builtin_fmaf(XT, wihf, bfv);                                \
    float a1g = __builtin_fmaf(XT, wihg, bgv);                                \
    float a1o = __builtin_fmaf(XT, wiho, bov);                                \
    float a2i = 0.0f, a2f = 0.0f, a2g = 0.0f, a2o = 0.0f;                     \
    {   /* h(t-1) broadcast: 4x same-address b128 per half (32 f16) */        \
        const float4 h0 = hb[0], h1 = hb[1], h2q = hb[2], h3 = hb[3];         \
        MACQ(h0, 0) MACQ(h1, 4) MACQ(h2q, 8) MACQ(h3, 12)                     \
    }                                                                         \
    const float ai = a1i + a2i, af_ = a1f + a2f;                              \
    const float ag = a1g + a2g, ao  = a1o + a2o;                              \
    /* accumulators are already -log2(e)-scaled: gate = rcp(1+exp2(a)) */     \
    const float gi = __builtin_amdgcn_rcpf(1.0f + __builtin_amdgcn_exp2f(ai));  \
    const float gf = __builtin_amdgcn_rcpf(1.0f + __builtin_amdgcn_exp2f(af_)); \
    const float go = __builtin_amdgcn_rcpf(1.0f + __builtin_amdgcn_exp2f(ao));  \
    const float gg = __builtin_fmaf(2.0f,                                     \
        __builtin_amdgcn_rcpf(1.0f + __builtin_amdgcn_exp2f(ag)), -1.0f);     \
    c = __builtin_fmaf(gf, c, gi * gg);                                       \
    const float th = __builtin_fmaf(2.0f,                                     \
        __builtin_amdgcn_rcpf(1.0f + __builtin_amdgcn_exp2f(c * N2L2E)), -1.0f); \
    h = go * th;                                                              \
    hbufh[wv][half][j] = (_Float16)h;        /* publish for next step */      \
} while (0)

    float xcur = xrow[j];                     // chunk 0 of this half's batch
    for (int tc = 0; tc < T_LEN / 32; ++tc) {
        xbuf[wv][half * 36 + j] = xcur;       // stage 32 steps of x
        float xnext = 0.0f;
        if (tc + 1 < T_LEN / 32) xnext = xrow[(tc + 1) * 32 + j];  // prefetch
        for (int t4 = 0; t4 < 8; ++t4) {
            const float4 xq = xb[t4];         // 4 steps of x, broadcast/half
            STEP(xq.x); STEP(xq.y); STEP(xq.z); STEP(xq.w);
        }
        xcur = xnext;
    }
#undef STEP
#undef MACQ
#undef PINALL
#undef PIN16

    // out[bb] = sum_j h[j]*W_fc[j] + b_fc  (butterfly within each half)
    float val = h * W_fc[j];
    #pragma unroll
    for (int off = 16; off >= 1; off >>= 1)
        val += __shfl_xor(val, off);
    if (j == 0 && bb < B) out[bb] = val + b_fc[0];
}

extern "C" void kernel_launch(void* const* d_in, const int* in_sizes, int n_in,
                              void* d_out, int out_size, void* d_ws, size_t ws_size,
                              hipStream_t stream) {
    const float* x    = (const float*)d_in[0];
    const float* W_ih = (const float*)d_in[1];
    const float* W_hh = (const float*)d_in[2];
    const float* b_ih = (const float*)d_in[3];
    const float* b_hh = (const float*)d_in[4];
    const float* W_fc = (const float*)d_in[5];
    const float* b_fc = (const float*)d_in[6];
    float* out = (float*)d_out;
    const int B = in_sizes[0] / T_LEN;        // 4096
    dim3 block(256);                          // 4 waves = 8 batch elements
    dim3 grid((B + 7) / 8);                   // 512 blocks -> 2 waves/SIMD
    reslstm_kernel<<<grid, block, 0, stream>>>(x, W_ih, W_hh, b_ih, b_hh,
                                               W_fc, b_fc, out, B);
}